// Round 7
// baseline (109.193 us; speedup 1.0000x reference)
//
#include <hip/hip_runtime.h>
#include <hip/hip_bf16.h>

#define N 8192
#define D 128
#define WEIGHT 0.01f
#define NTILES 64            // N / 128
#define NBLK 2080            // NTILES*(NTILES+1)/2  (tile count, for partial arrays)
#define TPB 4                // tiles per block (same block-row, consecutive bj)
#define GRID 544             // sum over bi of ceil((64-bi)/4)

typedef __bf16 bf16x8 __attribute__((ext_vector_type(8)));
typedef float floatx4 __attribute__((ext_vector_type(4)));

// ---- Kernel 1: L2-normalize rows (fp32) -> bf16, stored XOR-SWIZZLED:
//      16B chunk c of row r lands at chunk position c ^ (r & 15), so k_gram's
//      linear global_load_lds copy produces the conflict-free LDS layout.
__global__ __launch_bounds__(256) void k_norm(const float* __restrict__ x,
                                              __hip_bfloat16* __restrict__ fb) {
    int gid = blockIdx.x * 256 + threadIdx.x;   // 512 blocks
    int row = gid >> 4;                          // 16 threads per row
    int c   = gid & 15;                          // 16B chunk (8 bf16) per thread
    const float4* xr = (const float4*)(x + (size_t)row * D + c * 8);
    float4 f0 = xr[0], f1 = xr[1];
    float s = f0.x * f0.x + f0.y * f0.y + f0.z * f0.z + f0.w * f0.w
            + f1.x * f1.x + f1.y * f1.y + f1.z * f1.z + f1.w * f1.w;
    s += __shfl_xor(s, 1, 64);
    s += __shfl_xor(s, 2, 64);
    s += __shfl_xor(s, 4, 64);
    s += __shfl_xor(s, 8, 64);                   // 16-lane group = one row
    float inv = 1.0f / fmaxf(sqrtf(s), 1e-12f);
    union { __hip_bfloat16 h[8]; uint4 u; } pk;
    pk.h[0] = __float2bfloat16(f0.x * inv);
    pk.h[1] = __float2bfloat16(f0.y * inv);
    pk.h[2] = __float2bfloat16(f0.z * inv);
    pk.h[3] = __float2bfloat16(f0.w * inv);
    pk.h[4] = __float2bfloat16(f1.x * inv);
    pk.h[5] = __float2bfloat16(f1.y * inv);
    pk.h[6] = __float2bfloat16(f1.z * inv);
    pk.h[7] = __float2bfloat16(f1.w * inv);
    ((uint4*)fb)[(size_t)row * 16 + (c ^ (row & 15))] = pk.u;
}

// ---- Kernel 2: upper-triangle 128x128 tiles of sim = F F^T, pipelined.
//      Block = up to 4 tiles of one block-row bi: A staged once, B tiles
//      double-buffered via global_load_lds; next-B DMA is issued right after
//      the barrier and drains at the NEXT barrier (overlapped by a full
//      compute+epilogue phase). 98 KB LDS -> 1 block/CU, 4 waves (2x2, 64x64).
__global__ __launch_bounds__(256, 1) void k_gram(const __hip_bfloat16* __restrict__ fb,
                                                 float* __restrict__ Prow,
                                                 float* __restrict__ Pcol,
                                                 float* __restrict__ p,
                                                 float* __restrict__ ep) {
    // block -> (bi, bj0): row bi contributes ceil((64-bi)/4) blocks.
    int b = blockIdx.x;
    int bi = 0;
    for (; bi < NTILES; ++bi) {
        int cnt = (NTILES - bi + TPB - 1) >> 2;
        if (b < cnt) break;
        b -= cnt;
    }
    int bj0 = bi + b * TPB;
    int ntile = min(TPB, NTILES - bj0);

    __shared__ uint4 Ab[2048];           // A tile, pre-swizzled (32 KB)
    __shared__ uint4 Bb[2][2048];        // B tiles, double-buffered (64 KB)
    __shared__ float PR[2][2][128];      // [parity][wcol][row]
    __shared__ float PC[2][2][128];      // [parity][wrow][col]

    const int t = threadIdx.x;
    const int lane = t & 63;
    const int wid  = t >> 6;             // 4 waves, 2x2
    const int wrow = wid >> 1, wcol = wid & 1;
    const int col0 = lane & 15;
    const int quad = lane >> 4;
    const int rbase = bi * 128;
    const int tri0 = bi * NTILES - bi * (bi - 1) / 2;   // tile id of (bi, bi)

    const uint4* gf = (const uint4*)fb;

    // Initial staging: A and B0 (drained at the first barrier).
    {
        const uint4* gA = gf + (size_t)rbase * 16;
        const uint4* gB = gf + (size_t)(bj0 * 128) * 16;
        #pragma unroll
        for (int i = 0; i < 8; ++i) {
            int ca = wid * 512 + i * 64;
            __builtin_amdgcn_global_load_lds(
                (const __attribute__((address_space(1))) void*)(gA + ca + lane),
                (__attribute__((address_space(3))) void*)&Ab[ca], 16, 0, 0);
            __builtin_amdgcn_global_load_lds(
                (const __attribute__((address_space(1))) void*)(gB + ca + lane),
                (__attribute__((address_space(3))) void*)&Bb[0][ca], 16, 0, 0);
        }
    }

    for (int tt = 0; tt < ntile; ++tt) {
        const int cur = tt & 1;
        const int bjt = bj0 + tt;
        const int cbase = bjt * 128;
        const int tgid = tri0 + (bjt - bi);          // global tile id

        __syncthreads();   // drains in-flight DMA (overlapped by prev compute)

        // Issue next B tile into the buffer freed by the previous compute.
        if (tt + 1 < ntile) {
            const uint4* gBn = gf + (size_t)((bjt + 1) * 128) * 16;
            #pragma unroll
            for (int i = 0; i < 8; ++i) {
                int ca = wid * 512 + i * 64;
                __builtin_amdgcn_global_load_lds(
                    (const __attribute__((address_space(1))) void*)(gBn + ca + lane),
                    (__attribute__((address_space(3))) void*)&Bb[cur ^ 1][ca], 16, 0, 0);
            }
        }

        // Store previous tile's partials (written to PR/PC[parity] last iter).
        if (tt > 0) {
            int pprev = (tt - 1) & 1;
            int tprev = tgid - 1;
            if (t < 128) {
                Prow[(size_t)tprev * 128 + t] = PR[pprev][0][t] + PR[pprev][1][t];
            } else {
                int c = t - 128;
                Pcol[(size_t)tprev * 128 + c] = PC[pprev][0][c] + PC[pprev][1][c];
            }
        }

        // ---- Compute 128x128 tile from Ab, Bb[cur] ----
        floatx4 acc[4][4];
        #pragma unroll
        for (int a = 0; a < 4; ++a)
            #pragma unroll
            for (int c = 0; c < 4; ++c)
                acc[a][c] = (floatx4){0.0f, 0.0f, 0.0f, 0.0f};

        #pragma unroll
        for (int ks = 0; ks < 4; ++ks) {     // K = 128 = 4 x 32
            bf16x8 af[4], bfr[4];
            int j = ks * 4 + quad;
            int jsw = j ^ col0;              // fragment rows have (row & 15) == col0
            #pragma unroll
            for (int mt = 0; mt < 4; ++mt) {
                int rl = wrow * 64 + mt * 16 + col0;
                af[mt] = *(const bf16x8*)&Ab[rl * 16 + jsw];
            }
            #pragma unroll
            for (int nt = 0; nt < 4; ++nt) {
                int cl = wcol * 64 + nt * 16 + col0;
                bfr[nt] = *(const bf16x8*)&Bb[cur][cl * 16 + jsw];
            }
            #pragma unroll
            for (int mt = 0; mt < 4; ++mt)
                #pragma unroll
                for (int nt = 0; nt < 4; ++nt)
                    acc[mt][nt] = __builtin_amdgcn_mfma_f32_16x16x32_bf16(af[mt], bfr[nt], acc[mt][nt], 0, 0, 0);
        }

        // ---- Epilogue ----
        float v[16];                         // m -> row = wrow*64+(m>>2)*16+quad*4+(m&3)
        float colpart[4];                    // nt -> col = wcol*64 + nt*16 + col0
        #pragma unroll
        for (int m = 0; m < 16; ++m) v[m] = 0.0f;
        #pragma unroll
        for (int m = 0; m < 4; ++m) colpart[m] = 0.0f;

        if (bjt > bi + 1) {                  // fast path: all strictly upper
            #pragma unroll
            for (int mt = 0; mt < 4; ++mt)
                #pragma unroll
                for (int nt = 0; nt < 4; ++nt)
                    #pragma unroll
                    for (int reg = 0; reg < 4; ++reg) {
                        float e = __expf(acc[mt][nt][reg]);
                        v[mt * 4 + reg] += e;
                        colpart[nt] += e;
                    }
        } else {                             // diag / superdiag: mask + p extraction
            #pragma unroll
            for (int mt = 0; mt < 4; ++mt)
                #pragma unroll
                for (int nt = 0; nt < 4; ++nt)
                    #pragma unroll
                    for (int reg = 0; reg < 4; ++reg) {
                        int r = rbase + wrow * 64 + mt * 16 + quad * 4 + reg;
                        int c = cbase + wcol * 64 + nt * 16 + col0;
                        float s0 = acc[mt][nt][reg];
                        float e = __expf(s0);
                        if (c == r + 1) { p[r] = s0; ep[r] = e; }
                        e = (c > r) ? e : 0.0f;
                        v[mt * 4 + reg] += e;
                        colpart[nt] += e;
                    }
        }

        // Row sums: value-halving butterfly (15 shuffles, all lanes distinct rows).
        float v8[8];
        #pragma unroll
        for (int k = 0; k < 8; ++k) {
            float a = v[2 * k], bb = v[2 * k + 1];
            float give = (lane & 1) ? a : bb;
            float keep = (lane & 1) ? bb : a;
            v8[k] = keep + __shfl_xor(give, 1, 64);
        }
        float v4[4];
        #pragma unroll
        for (int k = 0; k < 4; ++k) {
            float a = v8[2 * k], bb = v8[2 * k + 1];
            float give = (lane & 2) ? a : bb;
            float keep = (lane & 2) ? bb : a;
            v4[k] = keep + __shfl_xor(give, 2, 64);
        }
        float v2[2];
        #pragma unroll
        for (int k = 0; k < 2; ++k) {
            float a = v4[2 * k], bb = v4[2 * k + 1];
            float give = (lane & 4) ? a : bb;
            float keep = (lane & 4) ? bb : a;
            v2[k] = keep + __shfl_xor(give, 4, 64);
        }
        {
            float a = v2[0], bb = v2[1];
            float give = (lane & 8) ? a : bb;
            float keep = (lane & 8) ? bb : a;
            float v1 = keep + __shfl_xor(give, 8, 64);
            int rowl = wrow * 64 + (col0 >> 2) * 16 + quad * 4 + (col0 & 3);
            PR[cur][wcol][rowl] = v1;
        }
        // Col sums: value-halving over lane bit4 then bit5 -> col = wcol*64 + lane.
        {
            float c2[2];
            #pragma unroll
            for (int k = 0; k < 2; ++k) {
                float a = colpart[2 * k];
                float bb = colpart[2 * k + 1];
                float give = (lane & 16) ? a : bb;
                float keep = (lane & 16) ? bb : a;
                c2[k] = keep + __shfl_xor(give, 16, 64);
            }
            float a = c2[0], bb = c2[1];
            float give = (lane & 32) ? a : bb;
            float keep = (lane & 32) ? bb : a;
            float cv = keep + __shfl_xor(give, 32, 64);
            PC[cur][wrow][wcol * 64 + lane] = cv;
        }
    }

    // Final tile's partials.
    __syncthreads();
    {
        int pprev = (ntile - 1) & 1;
        int tprev = tri0 + (bj0 + ntile - 1 - bi);
        if (t < 128) {
            Prow[(size_t)tprev * 128 + t] = PR[pprev][0][t] + PR[pprev][1][t];
        } else {
            int c = t - 128;
            Pcol[(size_t)tprev * 128 + c] = PC[pprev][0][c] + PC[pprev][1][c];
        }
    }
}

// ---- Kernel 3: gather partials -> U[r] (strict-upper row sums), L[c] (col sums).
__global__ __launch_bounds__(256) void k_reduce(const float* __restrict__ Prow,
                                                const float* __restrict__ Pcol,
                                                float* __restrict__ U,
                                                float* __restrict__ L) {
    int tile = blockIdx.x;               // 0..63
    int tid = threadIdx.x;
    int base_t = tile * NTILES - tile * (tile - 1) / 2;
    if (tid < 128) {
        float s = 0.0f;
        for (int bj = tile; bj < NTILES; ++bj)
            s += Prow[(size_t)(base_t + bj - tile) * 128 + tid];
        U[tile * 128 + tid] = s;
    } else {
        int c = tid - 128;
        float s = 0.0f;
        for (int bi = 0; bi <= tile; ++bi) {
            int bb = bi * NTILES - bi * (bi - 1) / 2 + (tile - bi);
            s += Pcol[(size_t)bb * 128 + c];
        }
        L[tile * 128 + c] = s;
    }
}

// ---- Kernel 4: loss = sum_i log(U_i + L_{i+1} - ep_i) - p_i; out = -W*loss/N
__global__ __launch_bounds__(1024) void k_final(const float* __restrict__ U,
                                                const float* __restrict__ L,
                                                const float* __restrict__ p,
                                                const float* __restrict__ ep,
                                                float* __restrict__ out) {
    __shared__ float swred[16];
    float s = 0.0f;
    for (int i = threadIdx.x; i < N - 1; i += 1024) {
        float tt = U[i] + L[i + 1] - ep[i];
        s += __logf(tt) - p[i];
    }
    #pragma unroll
    for (int m = 1; m < 64; m <<= 1) s += __shfl_xor(s, m, 64);
    int lane = threadIdx.x & 63, wid = threadIdx.x >> 6;
    if (lane == 0) swred[wid] = s;
    __syncthreads();
    if (threadIdx.x == 0) {
        float tot = 0.0f;
        #pragma unroll
        for (int w = 0; w < 16; ++w) tot += swred[w];
        out[0] = -WEIGHT * tot / (float)N;
    }
}

extern "C" void kernel_launch(void* const* d_in, const int* in_sizes, int n_in,
                              void* d_out, int out_size, void* d_ws, size_t ws_size,
                              hipStream_t stream) {
    const float* x = (const float*)d_in[0];
    float* out = (float*)d_out;
    char* ws = (char*)d_ws;
    __hip_bfloat16* fb = (__hip_bfloat16*)ws;                  // N*D*2 = 2 MB
    float* p    = (float*)(ws + (size_t)N * D * 2);            // N floats
    float* ep   = p + N;
    float* U    = ep + N;
    float* L    = U + N;
    float* Prow = L + N;                                       // NBLK*128 floats
    float* Pcol = Prow + (size_t)NBLK * 128;

    hipLaunchKernelGGL(k_norm,   dim3(512),  dim3(256),  0, stream, x, fb);
    hipLaunchKernelGGL(k_gram,   dim3(GRID), dim3(256),  0, stream, fb, Prow, Pcol, p, ep);
    hipLaunchKernelGGL(k_reduce, dim3(64),   dim3(256),  0, stream, Prow, Pcol, U, L);
    hipLaunchKernelGGL(k_final,  dim3(1),    dim3(1024), 0, stream, U, L, p, ep, out);
}

// Round 8
// 97.983 us; speedup vs baseline: 1.1144x; 1.1144x over previous
//
#include <hip/hip_runtime.h>
#include <hip/hip_bf16.h>

#define N 8192
#define D 128
#define WEIGHT 0.01f
#define NT2 32               // N / 256
#define NBLK2 528            // NT2*(NT2+1)/2 tiles of 256x256

typedef __bf16 bf16x8 __attribute__((ext_vector_type(8)));
typedef float floatx4 __attribute__((ext_vector_type(4)));

// ---- Kernel 1: L2-normalize rows (fp32) -> bf16, stored XOR-SWIZZLED:
//      16B chunk c of row r lands at chunk position c ^ (r & 15), so k_gram's
//      linear global_load_lds copy produces the conflict-free LDS layout.
__global__ __launch_bounds__(256) void k_norm(const float* __restrict__ x,
                                              __hip_bfloat16* __restrict__ fb) {
    int gid = blockIdx.x * 256 + threadIdx.x;   // 512 blocks
    int row = gid >> 4;                          // 16 threads per row
    int c   = gid & 15;                          // 16B chunk (8 bf16) per thread
    const float4* xr = (const float4*)(x + (size_t)row * D + c * 8);
    float4 f0 = xr[0], f1 = xr[1];
    float s = f0.x * f0.x + f0.y * f0.y + f0.z * f0.z + f0.w * f0.w
            + f1.x * f1.x + f1.y * f1.y + f1.z * f1.z + f1.w * f1.w;
    s += __shfl_xor(s, 1, 64);
    s += __shfl_xor(s, 2, 64);
    s += __shfl_xor(s, 4, 64);
    s += __shfl_xor(s, 8, 64);                   // 16-lane group = one row
    float inv = 1.0f / fmaxf(sqrtf(s), 1e-12f);
    union { __hip_bfloat16 h[8]; uint4 u; } pk;
    pk.h[0] = __float2bfloat16(f0.x * inv);
    pk.h[1] = __float2bfloat16(f0.y * inv);
    pk.h[2] = __float2bfloat16(f0.z * inv);
    pk.h[3] = __float2bfloat16(f0.w * inv);
    pk.h[4] = __float2bfloat16(f1.x * inv);
    pk.h[5] = __float2bfloat16(f1.y * inv);
    pk.h[6] = __float2bfloat16(f1.z * inv);
    pk.h[7] = __float2bfloat16(f1.w * inv);
    ((uint4*)fb)[(size_t)row * 16 + (c ^ (row & 15))] = pk.u;
}

// ---- Kernel 2: upper-triangle 256x256 tiles of sim = F F^T.
//      8 waves (4 wrow x 2 wcol), wave tile 64x128 (acc 4x8).
//      Staging 128 KB per 65536 outputs (2x less LDS+L2 traffic per output
//      than 128-tiles); 528 blocks = ~2 rounds/CU (4x fewer barrier drains).
//      LDS 134 KB -> 1 block/CU, 8 waves/CU.
__global__ __launch_bounds__(512, 2) void k_gram(const __hip_bfloat16* __restrict__ fb,
                                                 float* __restrict__ Prow,
                                                 float* __restrict__ Pcol,
                                                 float* __restrict__ p,
                                                 float* __restrict__ ep) {
    // Decode triangular linear index -> (bi, bj), bj >= bi, 32x32 tile grid.
    int b = blockIdx.x;                  // 0 .. 527
    int bi = 0;
    while ((bi + 1) * NT2 - (bi + 1) * bi / 2 <= b) ++bi;
    int bj = bi + (b - (bi * NT2 - bi * (bi - 1) / 2));

    __shared__ uint4 Ab[4096];           // 256 rows x 128 bf16, pre-swizzled (64 KB)
    __shared__ uint4 Bb[4096];           // (64 KB)
    __shared__ float PR[2][256];         // [wcol][row]
    __shared__ float PC[4][256];         // [wrow][col]

    const int t = threadIdx.x;
    const int lane = t & 63;
    const int wid  = t >> 6;             // 8 waves: 4x2
    const int wrow = wid & 3, wcol = wid >> 2;
    const int col0 = lane & 15;
    const int quad = lane >> 4;
    const int rbase = bi * 256, cbase = bj * 256;

    const uint4* gA = (const uint4*)fb + (size_t)rbase * 16;   // 4096 chunks
    const uint4* gB = (const uint4*)fb + (size_t)cbase * 16;
    #pragma unroll
    for (int i = 0; i < 8; ++i) {
        int ca = wid * 512 + i * 64;     // wave-uniform chunk base; lane adds *16B
        __builtin_amdgcn_global_load_lds(
            (const __attribute__((address_space(1))) void*)(gA + ca + lane),
            (__attribute__((address_space(3))) void*)&Ab[ca], 16, 0, 0);
        __builtin_amdgcn_global_load_lds(
            (const __attribute__((address_space(1))) void*)(gB + ca + lane),
            (__attribute__((address_space(3))) void*)&Bb[ca], 16, 0, 0);
    }
    __syncthreads();

    floatx4 acc[4][8];
    #pragma unroll
    for (int a = 0; a < 4; ++a)
        #pragma unroll
        for (int c = 0; c < 8; ++c)
            acc[a][c] = (floatx4){0.0f, 0.0f, 0.0f, 0.0f};

    #pragma unroll
    for (int ks = 0; ks < 4; ++ks) {     // K = 128 = 4 x 32
        bf16x8 af[4], bfr[8];
        int j = ks * 4 + quad;
        int jsw = j ^ col0;              // fragment rows have (row & 15) == col0
        #pragma unroll
        for (int mt = 0; mt < 4; ++mt) { // A[m=lane&15][k=quad*8+..]
            int rl = wrow * 64 + mt * 16 + col0;
            af[mt] = *(const bf16x8*)&Ab[rl * 16 + jsw];
        }
        #pragma unroll
        for (int nt = 0; nt < 8; ++nt) { // B^T[n=lane&15][k]
            int cl = wcol * 128 + nt * 16 + col0;
            bfr[nt] = *(const bf16x8*)&Bb[cl * 16 + jsw];
        }
        #pragma unroll
        for (int mt = 0; mt < 4; ++mt)
            #pragma unroll
            for (int nt = 0; nt < 8; ++nt)
                acc[mt][nt] = __builtin_amdgcn_mfma_f32_16x16x32_bf16(af[mt], bfr[nt], acc[mt][nt], 0, 0, 0);
    }

    // Epilogue: e = exp(sim); strict-upper mask only near the diagonal.
    float v[16];                         // m = mt*4+reg -> row = wrow*64+(m>>2)*16+quad*4+(m&3)
    float colpart[8];                    // nt -> col = wcol*128 + nt*16 + col0
    #pragma unroll
    for (int m = 0; m < 16; ++m) v[m] = 0.0f;
    #pragma unroll
    for (int m = 0; m < 8; ++m) colpart[m] = 0.0f;

    if (bj > bi + 1) {                   // fast path: all strictly upper
        #pragma unroll
        for (int mt = 0; mt < 4; ++mt)
            #pragma unroll
            for (int nt = 0; nt < 8; ++nt)
                #pragma unroll
                for (int reg = 0; reg < 4; ++reg) {
                    float e = __expf(acc[mt][nt][reg]);
                    v[mt * 4 + reg] += e;
                    colpart[nt] += e;
                }
    } else {                             // diag / next tile: mask + p extraction
        #pragma unroll
        for (int mt = 0; mt < 4; ++mt)
            #pragma unroll
            for (int nt = 0; nt < 8; ++nt)
                #pragma unroll
                for (int reg = 0; reg < 4; ++reg) {
                    int r = rbase + wrow * 64 + mt * 16 + quad * 4 + reg;
                    int c = cbase + wcol * 128 + nt * 16 + col0;
                    float s0 = acc[mt][nt][reg];
                    float e = __expf(s0);
                    if (c == r + 1) { p[r] = s0; ep[r] = e; }
                    e = (c > r) ? e : 0.0f;
                    v[mt * 4 + reg] += e;
                    colpart[nt] += e;
                }
    }

    // Row sums: value-halving butterfly (15 shuffles, all lanes distinct rows).
    float v8[8];
    #pragma unroll
    for (int k = 0; k < 8; ++k) {
        float a = v[2 * k], bb = v[2 * k + 1];
        float give = (lane & 1) ? a : bb;
        float keep = (lane & 1) ? bb : a;
        v8[k] = keep + __shfl_xor(give, 1, 64);
    }
    float v4[4];
    #pragma unroll
    for (int k = 0; k < 4; ++k) {
        float a = v8[2 * k], bb = v8[2 * k + 1];
        float give = (lane & 2) ? a : bb;
        float keep = (lane & 2) ? bb : a;
        v4[k] = keep + __shfl_xor(give, 2, 64);
    }
    float v2[2];
    #pragma unroll
    for (int k = 0; k < 2; ++k) {
        float a = v4[2 * k], bb = v4[2 * k + 1];
        float give = (lane & 4) ? a : bb;
        float keep = (lane & 4) ? bb : a;
        v2[k] = keep + __shfl_xor(give, 4, 64);
    }
    {
        float a = v2[0], bb = v2[1];
        float give = (lane & 8) ? a : bb;
        float keep = (lane & 8) ? bb : a;
        float v1 = keep + __shfl_xor(give, 8, 64);
        int rowl = wrow * 64 + (col0 >> 2) * 16 + quad * 4 + (col0 & 3);
        PR[wcol][rowl] = v1;
    }
    // Col sums: value-halving over lane bit4 then bit5.
    // End state: lane holds c2[m] = col sum for nt = m*4 + quad,
    // i.e. col = wcol*128 + m*64 + lane.
    {
        float c4[4];
        #pragma unroll
        for (int k = 0; k < 4; ++k) {
            float a = colpart[2 * k];        // nt even
            float bb = colpart[2 * k + 1];   // nt odd
            float give = (lane & 16) ? a : bb;
            float keep = (lane & 16) ? bb : a;
            c4[k] = keep + __shfl_xor(give, 16, 64);
        }
        #pragma unroll
        for (int k = 0; k < 2; ++k) {
            float a = c4[2 * k], bb = c4[2 * k + 1];
            float give = (lane & 32) ? a : bb;
            float keep = (lane & 32) ? bb : a;
            float cv = keep + __shfl_xor(give, 32, 64);
            PC[wrow][wcol * 128 + k * 64 + lane] = cv;
        }
    }
    __syncthreads();

    if (t < 256) {
        Prow[(size_t)blockIdx.x * 256 + t] = PR[0][t] + PR[1][t];
    } else {
        int c = t - 256;
        Pcol[(size_t)blockIdx.x * 256 + c] = PC[0][c] + PC[1][c] + PC[2][c] + PC[3][c];
    }
}

// ---- Kernel 3: gather partials -> U[r] (strict-upper row sums), L[c] (col sums).
__global__ __launch_bounds__(512) void k_reduce(const float* __restrict__ Prow,
                                                const float* __restrict__ Pcol,
                                                float* __restrict__ U,
                                                float* __restrict__ L) {
    int tile = blockIdx.x;               // 0..31
    int tid = threadIdx.x;
    int base_t = tile * NT2 - tile * (tile - 1) / 2;
    if (tid < 256) {
        float s = 0.0f;
        for (int bj = tile; bj < NT2; ++bj)
            s += Prow[(size_t)(base_t + bj - tile) * 256 + tid];
        U[tile * 256 + tid] = s;
    } else {
        int c = tid - 256;
        float s = 0.0f;
        for (int bi = 0; bi <= tile; ++bi) {
            int bb = bi * NT2 - bi * (bi - 1) / 2 + (tile - bi);
            s += Pcol[(size_t)bb * 256 + c];
        }
        L[tile * 256 + c] = s;
    }
}

// ---- Kernel 4: loss = sum_i log(U_i + L_{i+1} - ep_i) - p_i; out = -W*loss/N
__global__ __launch_bounds__(1024) void k_final(const float* __restrict__ U,
                                                const float* __restrict__ L,
                                                const float* __restrict__ p,
                                                const float* __restrict__ ep,
                                                float* __restrict__ out) {
    __shared__ float swred[16];
    float s = 0.0f;
    for (int i = threadIdx.x; i < N - 1; i += 1024) {
        float tt = U[i] + L[i + 1] - ep[i];
        s += __logf(tt) - p[i];
    }
    #pragma unroll
    for (int m = 1; m < 64; m <<= 1) s += __shfl_xor(s, m, 64);
    int lane = threadIdx.x & 63, wid = threadIdx.x >> 6;
    if (lane == 0) swred[wid] = s;
    __syncthreads();
    if (threadIdx.x == 0) {
        float tot = 0.0f;
        #pragma unroll
        for (int w = 0; w < 16; ++w) tot += swred[w];
        out[0] = -WEIGHT * tot / (float)N;
    }
}

extern "C" void kernel_launch(void* const* d_in, const int* in_sizes, int n_in,
                              void* d_out, int out_size, void* d_ws, size_t ws_size,
                              hipStream_t stream) {
    const float* x = (const float*)d_in[0];
    float* out = (float*)d_out;
    char* ws = (char*)d_ws;
    __hip_bfloat16* fb = (__hip_bfloat16*)ws;                  // N*D*2 = 2 MB
    float* p    = (float*)(ws + (size_t)N * D * 2);            // N floats
    float* ep   = p + N;
    float* U    = ep + N;
    float* L    = U + N;
    float* Prow = L + N;                                       // NBLK2*256 floats
    float* Pcol = Prow + (size_t)NBLK2 * 256;

    hipLaunchKernelGGL(k_norm,   dim3(512),   dim3(256),  0, stream, x, fb);
    hipLaunchKernelGGL(k_gram,   dim3(NBLK2), dim3(512),  0, stream, fb, Prow, Pcol, p, ep);
    hipLaunchKernelGGL(k_reduce, dim3(32),    dim3(512),  0, stream, Prow, Pcol, U, L);
    hipLaunchKernelGGL(k_final,  dim3(1),     dim3(1024), 0, stream, U, L, p, ep, out);
}